// Round 6
// baseline (874.223 us; speedup 1.0000x reference)
//
#include <hip/hip_runtime.h>

#define NB 65536
#define CBLK 256

typedef unsigned long long u64;
typedef __attribute__((ext_vector_type(8))) short short8;   // 8 bf16 (guide-verified typing)
typedef __attribute__((ext_vector_type(4))) float f32x4;

union FragAB { unsigned short us[8]; unsigned w[4]; short8 v; };

__device__ __forceinline__ float fast_rcp(float x){ return __builtin_amdgcn_rcpf(x); }
__device__ __forceinline__ float sigf(float x){ return fast_rcp(1.0f + __expf(-x)); }
__device__ __forceinline__ float tanh_fast(float x){ return 1.0f - 2.0f*fast_rcp(1.0f + __expf(2.0f*x)); }

__device__ __forceinline__ unsigned short f2bf(float f){
    union { float f; unsigned u; } x; x.f = f;
    unsigned r = x.u + 0x7FFFu + ((x.u >> 16) & 1u);   // RNE
    return (unsigned short)(r >> 16);
}
__device__ __forceinline__ float bf2f(unsigned short h){
    union { unsigned u; float f; } x; x.u = ((unsigned)h) << 16; return x.f;
}

// ==================== SPLIT PATH ====================
// Kernel A: conv1+bn1+relu -> conv2+bn2+relu, position-parallel (18 threads/sample,
// 5 positions each). FMA chains textually identical to the fused kernel -> hv values
// bit-exact. Writes hv[site][sample] (f32, coalesced) for sites 0..1055 and per-group
// partial sums for avg. VGPR ~80 -> ~6 waves/SIMD (vs 1 for the fused kernel).
__global__ __launch_bounds__(256)
void k_conv_a(const float* __restrict__ x,
              const float* __restrict__ c1w, const float* __restrict__ c1b,
              const float* __restrict__ b1g, const float* __restrict__ b1b,
              const float* __restrict__ b1m, const float* __restrict__ b1v,
              const float* __restrict__ c2w, const float* __restrict__ c2b,
              const float* __restrict__ b2g, const float* __restrict__ b2b,
              const float* __restrict__ b2m, const float* __restrict__ b2v,
              float* __restrict__ hv, float* __restrict__ pavg)
{
    const int g = blockIdx.x >> 8;                       // position group 0..17 (uniform/block)
    const int s = ((blockIdx.x & 255) << 8) + threadIdx.x;
    const float* xr = x + (size_t)s * 360;

    float w1f[6][5], c1f[6];
    #pragma unroll
    for (int c = 0; c < 6; ++c) {
        float sc = b1g[c] / sqrtf(b1v[c] + 1e-5f);
        #pragma unroll
        for (int j = 0; j < 5; ++j) w1f[c][j] = c1w[c*5+j] * sc;
        c1f[c] = (c1b[c] - b1m[c]) * sc + b1b[c];
    }
    float s2v[12], t2v[12];
    #pragma unroll
    for (int c = 0; c < 12; ++c) {
        float sc = b2g[c] / sqrtf(b2v[c] + 1e-5f);
        s2v[c] = sc;
        t2v[c] = (c2b[c] - b2m[c]) * sc + b2b[c];
    }

    // window xw[i] = x[20g-4+i], i = 0..27 (7 float4; pad vecs are wave-uniform)
    float xw[28];
    #pragma unroll
    for (int e = 0; e < 7; ++e) {
        const int gi = 20*g - 4 + 4*e;
        float4 v;
        if ((g == 0 && e == 0) || (g == 17 && e == 6)) v = make_float4(0.f,0.f,0.f,0.f);
        else v = *(const float4*)(xr + gi);
        xw[4*e+0] = v.x; xw[4*e+1] = v.y; xw[4*e+2] = v.z; xw[4*e+3] = v.w;
    }

    // hA = conv1 site 10g-1 (covers x[20g-4..20g] = xw[0..4]); pad-zero site for g==0.
    float hA[6], hB[6], hC[6];
    if (g == 0) {
        #pragma unroll
        for (int c = 0; c < 6; ++c) hA[c] = 0.f;
    } else {
        #pragma unroll
        for (int c = 0; c < 6; ++c) {
            float a = c1f[c] + w1f[c][0]*xw[0] + w1f[c][1]*xw[1] + w1f[c][2]*xw[2]
                             + w1f[c][3]*xw[3] + w1f[c][4]*xw[4];
            hA[c] = fmaxf(a, 0.f);
        }
    }

    float sum12p[12];
    #pragma unroll
    for (int c = 0; c < 12; ++c) sum12p[c] = 0.f;

    float* hvs = hv + s;
    #pragma unroll
    for (int pi = 0; pi < 5; ++pi) {
        const int P = 5*g + pi;
        const float xv0 = xw[4*pi+2], xv1 = xw[4*pi+3], xv2 = xw[4*pi+4],
                    xv3 = xw[4*pi+5], xv4 = xw[4*pi+6], xv5 = xw[4*pi+7],
                    xv6 = xw[4*pi+8];
        #pragma unroll
        for (int c = 0; c < 6; ++c) {
            float aB = c1f[c] + w1f[c][0]*xv0 + w1f[c][1]*xv1 + w1f[c][2]*xv2
                              + w1f[c][3]*xv3 + w1f[c][4]*xv4;
            float aC = c1f[c] + w1f[c][0]*xv2 + w1f[c][1]*xv3 + w1f[c][2]*xv4
                              + w1f[c][3]*xv5 + w1f[c][4]*xv6;
            hB[c] = fmaxf(aB, 0.f);
            hC[c] = fmaxf(aC, 0.f);
        }
        #pragma unroll
        for (int c2 = 0; c2 < 12; ++c2) {
            float acc = 0.f;
            #pragma unroll
            for (int c1 = 0; c1 < 6; ++c1) {
                const float* wp = c2w + c2*18 + c1*3;
                acc += wp[0]*hA[c1] + wp[1]*hB[c1] + wp[2]*hC[c1];
            }
            float hvv = fmaxf(acc*s2v[c2] + t2v[c2], 0.f);
            sum12p[c2] += hvv;
            if (P < 88) hvs[(size_t)(12*P + c2) * NB] = hvv;   // sites >= 1056 feed avg only
        }
        #pragma unroll
        for (int c = 0; c < 6; ++c) hA[c] = hC[c];
    }
    #pragma unroll
    for (int c2 = 0; c2 < 12; ++c2)
        pavg[(size_t)(g*12 + c2)*NB + s] = sum12p[c2];
}

// Kernel B: LIF1 -> LIF2 scan (identical update code -> bit-exact spikes) streaming
// hv[site][sample] coalesced; combines the 18 avg partials. Memory-bound.
__global__ __launch_bounds__(256)
void k_lif_b(const float* __restrict__ hv, const float* __restrict__ pavg,
             u64* __restrict__ spk, float* __restrict__ avg)
{
    const int s = blockIdx.x * 256 + threadIdx.x;

    float m1[33], m2[33];
    #pragma unroll
    for (int k = 0; k < 33; ++k) { m1[k] = 0.f; m2[k] = 0.f; }

    const float* hs = hv + s;
    #pragma unroll 1
    for (int ss = 0; ss < 8; ++ss) {
        unsigned curlo = 0u, curhi = 0u;
        #pragma unroll
        for (int i = 0; i < 132; ++i) {
            const int kk = i % 33;                         // 132 = 4*33 -> static
            float hvv = hs[(size_t)(132*ss + i) * NB];
            float v1 = 0.95f*m1[kk] + hvv;
            bool s1 = (v1 > 0.5f);
            m1[kk] = s1 ? 0.f : v1;
            float v2 = 0.9f*m2[kk] + (s1 ? 1.f : 0.f);
            bool sp2 = (v2 > 0.6f);
            m2[kk] = sp2 ? 0.f : v2;
            if (sp2) { if (kk < 32) curlo |= (1u << kk); else curhi |= 1u; }
            if (kk == 32) {
                spk[(size_t)(4*ss + i/33)*NB + s] = ((u64)curhi << 32) | (u64)curlo;
                curlo = 0u; curhi = 0u;
            }
        }
    }
    #pragma unroll
    for (int c = 0; c < 12; ++c) {
        float t = 0.f;
        #pragma unroll
        for (int gg = 0; gg < 18; ++gg) t += pavg[(size_t)(gg*12 + c)*NB + s];
        avg[(size_t)c*NB + s] = t / 90.0f;
    }
}

// ==================== FALLBACK: fused conv+LIF (round-5, known-pass) ====================
__global__ __launch_bounds__(CBLK)
void k_conv_fused(const float* __restrict__ x,
                  const float* __restrict__ c1w, const float* __restrict__ c1b,
                  const float* __restrict__ b1g, const float* __restrict__ b1b,
                  const float* __restrict__ b1m, const float* __restrict__ b1v,
                  const float* __restrict__ c2w, const float* __restrict__ c2b,
                  const float* __restrict__ b2g, const float* __restrict__ b2b,
                  const float* __restrict__ b2m, const float* __restrict__ b2v,
                  u64* __restrict__ spk,
                  float* __restrict__ avg)
{
    const int b = blockIdx.x * CBLK + threadIdx.x;
    const float* xr = x + (size_t)b * 360;

    float w1f[6][5], c1f[6];
    #pragma unroll
    for (int c = 0; c < 6; ++c) {
        float s = b1g[c] / sqrtf(b1v[c] + 1e-5f);
        #pragma unroll
        for (int j = 0; j < 5; ++j) w1f[c][j] = c1w[c*5+j] * s;
        c1f[c] = (c1b[c] - b1m[c]) * s + b1b[c];
    }
    float s2v[12], t2v[12];
    #pragma unroll
    for (int c = 0; c < 12; ++c) {
        float s = b2g[c] / sqrtf(b2v[c] + 1e-5f);
        s2v[c] = s;
        t2v[c] = (c2b[c] - b2m[c]) * s + b2b[c];
    }

    float m1[33], m2[33];
    #pragma unroll
    for (int k = 0; k < 33; ++k) { m1[k] = 0.f; m2[k] = 0.f; }

    float sum12[12];
    #pragma unroll
    for (int c = 0; c < 12; ++c) sum12[c] = 0.f;

    float hA[6], hB[6], hC[6];
    #pragma unroll
    for (int c = 0; c < 6; ++c) hA[c] = 0.f;

    #pragma unroll 1
    for (int ss = 0; ss < 8; ++ss) {
        float xw[52];
        #pragma unroll
        for (int e = 0; e < 13; ++e) {
            int gi = 44*ss - 4 + 4*e;
            float4 v;
            if (gi >= 0) v = *(const float4*)(xr + gi);
            else         v = make_float4(0.f, 0.f, 0.f, 0.f);
            xw[4*e+0] = v.x; xw[4*e+1] = v.y; xw[4*e+2] = v.z; xw[4*e+3] = v.w;
        }

        unsigned curlo = 0u, curhi = 0u;
        #pragma unroll
        for (int pi = 0; pi < 11; ++pi) {
            const float xv0 = xw[4*pi+2], xv1 = xw[4*pi+3], xv2 = xw[4*pi+4],
                        xv3 = xw[4*pi+5], xv4 = xw[4*pi+6], xv5 = xw[4*pi+7],
                        xv6 = xw[4*pi+8];
            #pragma unroll
            for (int c = 0; c < 6; ++c) {
                float aB = c1f[c] + w1f[c][0]*xv0 + w1f[c][1]*xv1 + w1f[c][2]*xv2
                                  + w1f[c][3]*xv3 + w1f[c][4]*xv4;
                float aC = c1f[c] + w1f[c][0]*xv2 + w1f[c][1]*xv3 + w1f[c][2]*xv4
                                  + w1f[c][3]*xv5 + w1f[c][4]*xv6;
                hB[c] = fmaxf(aB, 0.f);
                hC[c] = fmaxf(aC, 0.f);
            }
            #pragma unroll
            for (int c2 = 0; c2 < 12; ++c2) {
                float acc = 0.f;
                #pragma unroll
                for (int c1 = 0; c1 < 6; ++c1) {
                    const float* wp = c2w + c2*18 + c1*3;
                    acc += wp[0]*hA[c1] + wp[1]*hB[c1] + wp[2]*hC[c1];
                }
                float hvv = fmaxf(acc*s2v[c2] + t2v[c2], 0.f);
                sum12[c2] += hvv;

                const int ls = 12*pi + c2;
                const int kk = ls % 33;
                float v1 = 0.95f*m1[kk] + hvv;
                bool s1 = (v1 > 0.5f);
                m1[kk] = s1 ? 0.f : v1;
                float v2 = 0.9f*m2[kk] + (s1 ? 1.f : 0.f);
                bool sp2 = (v2 > 0.6f);
                m2[kk] = sp2 ? 0.f : v2;
                if (sp2) { if (kk < 32) curlo |= (1u << kk); else curhi |= 1u; }
                if (kk == 32) {
                    spk[(size_t)(4*ss + ls/33)*NB + b] = ((u64)curhi << 32) | (u64)curlo;
                    curlo = 0u; curhi = 0u;
                }
            }
            #pragma unroll
            for (int c = 0; c < 6; ++c) hA[c] = hC[c];
        }
    }

    {
        float xw2[13];
        float4 a0 = *(const float4*)(xr + 348);
        float4 a1 = *(const float4*)(xr + 352);
        float4 a2 = *(const float4*)(xr + 356);
        xw2[0]=a0.x; xw2[1]=a0.y; xw2[2]=a0.z; xw2[3]=a0.w;
        xw2[4]=a1.x; xw2[5]=a1.y; xw2[6]=a1.z; xw2[7]=a1.w;
        xw2[8]=a2.x; xw2[9]=a2.y; xw2[10]=a2.z; xw2[11]=a2.w;
        xw2[12]=0.f;
        #pragma unroll
        for (int pt = 0; pt < 2; ++pt) {
            const float xv0 = xw2[2+4*pt], xv1 = xw2[3+4*pt], xv2 = xw2[4+4*pt],
                        xv3 = xw2[5+4*pt], xv4 = xw2[6+4*pt], xv5 = xw2[7+4*pt],
                        xv6 = xw2[8+4*pt];
            #pragma unroll
            for (int c = 0; c < 6; ++c) {
                float aB = c1f[c] + w1f[c][0]*xv0 + w1f[c][1]*xv1 + w1f[c][2]*xv2
                                  + w1f[c][3]*xv3 + w1f[c][4]*xv4;
                float aC = c1f[c] + w1f[c][0]*xv2 + w1f[c][1]*xv3 + w1f[c][2]*xv4
                                  + w1f[c][3]*xv5 + w1f[c][4]*xv6;
                hB[c] = fmaxf(aB, 0.f);
                hC[c] = fmaxf(aC, 0.f);
            }
            #pragma unroll
            for (int c2 = 0; c2 < 12; ++c2) {
                float acc = 0.f;
                #pragma unroll
                for (int c1 = 0; c1 < 6; ++c1) {
                    const float* wp = c2w + c2*18 + c1*3;
                    acc += wp[0]*hA[c1] + wp[1]*hB[c1] + wp[2]*hC[c1];
                }
                sum12[c2] += fmaxf(acc*s2v[c2] + t2v[c2], 0.f);
            }
            #pragma unroll
            for (int c = 0; c < 6; ++c) hA[c] = hC[c];
        }
    }
    #pragma unroll
    for (int c = 0; c < 12; ++c) avg[(size_t)c*NB + b] = sum12[c] / 90.0f;
}

// ============ Kernel: MFMA LSTM (split-bf16) + heads — ZERO LDS (round-5, unchanged) ============
__global__ __launch_bounds__(256, 2)
void k_lstm_mfma(const u64* __restrict__ spk,
                 const float* __restrict__ avg,
                 const float* __restrict__ wih, const float* __restrict__ whh,
                 const float* __restrict__ bih, const float* __restrict__ bhh,
                 const float* __restrict__ rw1, const float* __restrict__ rb1,
                 const float* __restrict__ rw2, const float* __restrict__ rb2,
                 const float* __restrict__ fw,  const float* __restrict__ fb,
                 const float* __restrict__ cw1, const float* __restrict__ cb1,
                 const float* __restrict__ cw2, const float* __restrict__ cb2,
                 float* __restrict__ out)
{
    const int tid  = threadIdx.x;
    const int lane = tid & 63;
    const int wv   = __builtin_amdgcn_readfirstlane(tid >> 6);
    const int q    = lane >> 4;
    const int n16  = lane & 15;
    const int sample = blockIdx.x * 64 + wv * 16 + n16;
    const int q8 = q * 8;

    short8 WihHi[6][2], WihLo[6], WhhHi[6], WhhLo[6];
    #pragma unroll
    for (int m = 0; m < 6; ++m) {
        const int rowA = 16*m + n16;
        const int u    = rowA >> 2;
        const int gt   = rowA & 3;
        const float* wr = wih + (gt*24 + u)*33;
        FragAB fh, fl;
        #pragma unroll
        for (int j = 0; j < 8; ++j) {
            float v = wr[q8 + j];
            unsigned short h = f2bf(v);
            fh.us[j] = h;
            fl.us[j] = f2bf(v - bf2f(h));
        }
        WihHi[m][0] = fh.v; WihLo[m] = fl.v;

        FragAB f1z;
        #pragma unroll
        for (int j = 0; j < 8; ++j) f1z.us[j] = 0;
        if (q == 0) {
            f1z.us[0] = f2bf(wr[32]);
            float bs = bih[gt*24 + u] + bhh[gt*24 + u];
            unsigned short bh = f2bf(bs);
            f1z.us[1] = bh;
            f1z.us[2] = f2bf(bs - bf2f(bh));
        }
        WihHi[m][1] = f1z.v;

        const float* hr = whh + (gt*24 + u)*24;
        FragAB gh, gl;
        #pragma unroll
        for (int j = 0; j < 8; ++j) {
            float v = (j < 6) ? hr[4*j + q] : 0.f;
            unsigned short h = f2bf(v);
            gh.us[j] = (j < 6) ? h : (unsigned short)0;
            gl.us[j] = (j < 6) ? f2bf(v - bf2f(h)) : (unsigned short)0;
        }
        WhhHi[m] = gh.v; WhhLo[m] = gl.v;
    }

    float av3[3];
    #pragma unroll
    for (int i = 0; i < 3; ++i) av3[i] = avg[(size_t)(3*q + i)*NB + sample];

    float cst[6], hreg[6];
    #pragma unroll
    for (int m = 0; m < 6; ++m) { cst[m] = 0.f; hreg[m] = 0.f; }

    const u64* sp = spk + sample;
    u64 w0 = sp[0];
    u64 w1 = sp[(size_t)1*NB];

    #pragma unroll 1
    for (int t = 0; t < 32; ++t) {
        const u64 wcur = w0;

        u64 w2 = 0;
        if (t < 30) w2 = sp[(size_t)(t+2)*NB];

        FragAB BH, BL;
        {
            union { float f; unsigned u; } hu[6];
            #pragma unroll
            for (int m = 0; m < 6; ++m) hu[m].f = hreg[m];
            #pragma unroll
            for (int jp = 0; jp < 3; ++jp) {
                unsigned u0 = hu[2*jp].u, u1 = hu[2*jp+1].u;
                BH.w[jp] = (u0 >> 16) | (u1 & 0xFFFF0000u);
                union { unsigned u; float f; } t0, t1;
                t0.u = u0 & 0xFFFF0000u; t1.u = u1 & 0xFFFF0000u;
                BL.w[jp] = (unsigned)f2bf(hu[2*jp].f - t0.f)
                         | ((unsigned)f2bf(hu[2*jp+1].f - t1.f) << 16);
            }
            BH.w[3] = 0u; BL.w[3] = 0u;
        }

        const unsigned lo32 = (unsigned)wcur;
        const unsigned hi32 = (unsigned)(wcur >> 32);
        FragAB bs0;
        {
            const unsigned byt = (lo32 >> q8) & 0xFFu;
            #pragma unroll
            for (int p = 0; p < 4; ++p) {
                unsigned e0 = (byt >> (2*p)) & 1u;
                unsigned e1 = (byt >> (2*p+1)) & 1u;
                bs0.w[p] = (e0 ? 0x3F80u : 0u) | (e1 ? 0x3F800000u : 0u);
            }
        }
        FragAB bs1;
        bs1.w[0] = 0x3F800000u | ((hi32 & 1u) ? 0x3F80u : 0u);
        bs1.w[1] = 0x00003F80u;
        bs1.w[2] = 0u; bs1.w[3] = 0u;

        f32x4 acc[6];
        #pragma unroll
        for (int m = 0; m < 6; ++m) {
            f32x4 a = {0.f, 0.f, 0.f, 0.f};
            a = __builtin_amdgcn_mfma_f32_16x16x32_bf16(WihHi[m][0], bs0.v, a, 0, 0, 0);
            a = __builtin_amdgcn_mfma_f32_16x16x32_bf16(WihLo[m],    bs0.v, a, 0, 0, 0);
            a = __builtin_amdgcn_mfma_f32_16x16x32_bf16(WihHi[m][1], bs1.v, a, 0, 0, 0);
            a = __builtin_amdgcn_mfma_f32_16x16x32_bf16(WhhHi[m],    BH.v,  a, 0, 0, 0);
            a = __builtin_amdgcn_mfma_f32_16x16x32_bf16(WhhLo[m],    BH.v,  a, 0, 0, 0);
            a = __builtin_amdgcn_mfma_f32_16x16x32_bf16(WhhHi[m],    BL.v,  a, 0, 0, 0);
            acc[m] = a;
        }

        #pragma unroll
        for (int m = 0; m < 6; ++m) {
            float ii = sigf(acc[m][0]);
            float ff = sigf(acc[m][1]);
            float gg = tanh_fast(acc[m][2]);
            float oo = sigf(acc[m][3]);
            float cn = ff*cst[m] + ii*gg;
            cst[m] = cn;
            hreg[m] = oo * tanh_fast(cn);
        }
        w0 = w1;
        w1 = w2;
    }

    float f1v[12];
    #pragma unroll
    for (int r = 0; r < 12; ++r) {
        float a = 0.f;
        #pragma unroll
        for (int m = 0; m < 6; ++m) a += rw1[r*36 + 4*m + q] * hreg[m];
        #pragma unroll
        for (int i = 0; i < 3; ++i) a += rw1[r*36 + 24 + 3*q + i] * av3[i];
        a += __shfl_xor(a, 16);
        a += __shfl_xor(a, 32);
        f1v[r] = fmaxf(a + rb1[r], 0.f);
    }
    float z0 = rb2[0], z1 = rb2[1];
    #pragma unroll
    for (int r = 0; r < 12; ++r) { z0 += rw2[r]*f1v[r]; z1 += rw2[12+r]*f1v[r]; }
    float mz = fmaxf(z0, z1);
    float e0 = 0.7f*__expf(z0 - mz), e1 = 0.3f*__expf(z1 - mz);
    float alpha = e0 * fast_rcp(e0 + e1);

    float ha[6], sa3[3];
    #pragma unroll
    for (int m = 0; m < 6; ++m) ha[m] = hreg[m]*alpha;
    #pragma unroll
    for (int i = 0; i < 3; ++i) sa3[i] = av3[i]*(1.f - alpha);

    float fuv[24];
    #pragma unroll
    for (int r = 0; r < 24; ++r) {
        float a = 0.f;
        #pragma unroll
        for (int m = 0; m < 6; ++m) a += fw[r*36 + 4*m + q] * ha[m];
        #pragma unroll
        for (int i = 0; i < 3; ++i) a += fw[r*36 + 24 + 3*q + i] * sa3[i];
        a += __shfl_xor(a, 16);
        a += __shfl_xor(a, 32);
        fuv[r] = fmaxf(a + fb[r], 0.f);
    }
    float c1r[3];
    #pragma unroll
    for (int k = 0; k < 3; ++k) {
        const int r = 3*q + k;
        float a = cb1[r];
        #pragma unroll
        for (int u2 = 0; u2 < 24; ++u2) a += cw1[r*24 + u2] * fuv[u2];
        c1r[k] = fmaxf(a, 0.f);
    }
    #pragma unroll
    for (int o = 0; o < 5; ++o) {
        float a = 0.f;
        #pragma unroll
        for (int k = 0; k < 3; ++k) a += cw2[o*12 + 3*q + k] * c1r[k];
        a += __shfl_xor(a, 16);
        a += __shfl_xor(a, 32);
        if (q == 0) out[(size_t)sample*5 + o] = a + cb2[o];
    }
}

extern "C" void kernel_launch(void* const* d_in, const int* in_sizes, int n_in,
                              void* d_out, int out_size, void* d_ws, size_t ws_size,
                              hipStream_t stream) {
    const float* x    = (const float*)d_in[0];
    const float* c1w  = (const float*)d_in[1];
    const float* c1b  = (const float*)d_in[2];
    const float* b1g  = (const float*)d_in[3];
    const float* b1b  = (const float*)d_in[4];
    const float* b1m  = (const float*)d_in[5];
    const float* b1v  = (const float*)d_in[6];
    const float* c2w  = (const float*)d_in[7];
    const float* c2b  = (const float*)d_in[8];
    const float* b2g  = (const float*)d_in[9];
    const float* b2b  = (const float*)d_in[10];
    const float* b2m  = (const float*)d_in[11];
    const float* b2v  = (const float*)d_in[12];
    const float* wih  = (const float*)d_in[13];
    const float* whh  = (const float*)d_in[14];
    const float* bih  = (const float*)d_in[15];
    const float* bhh  = (const float*)d_in[16];
    const float* rw1  = (const float*)d_in[17];
    const float* rb1  = (const float*)d_in[18];
    const float* rw2  = (const float*)d_in[19];
    const float* rb2  = (const float*)d_in[20];
    const float* fw   = (const float*)d_in[21];
    const float* fb   = (const float*)d_in[22];
    const float* cw1  = (const float*)d_in[23];
    const float* cb1  = (const float*)d_in[24];
    const float* cw2  = (const float*)d_in[25];
    const float* cb2  = (const float*)d_in[26];
    float* out = (float*)d_out;

    // workspace layout: [spk 16.78MB][avg 3.15MB][pavg 56.62MB][hv 276.82MB]
    const size_t SPK_B  = (size_t)32 * NB * sizeof(u64);       //  16,777,216
    const size_t AVG_B  = (size_t)12 * NB * sizeof(float);     //   3,145,728
    const size_t PAVG_B = (size_t)18 * 12 * NB * sizeof(float);//  56,623,104
    const size_t HV_B   = (size_t)1056 * NB * sizeof(float);   // 276,824,064
    const size_t NEED   = SPK_B + AVG_B + PAVG_B + HV_B;       // ~353 MB

    u64*   spk  = (u64*)d_ws;
    float* avg  = (float*)((char*)d_ws + SPK_B);
    float* pavg = (float*)((char*)d_ws + SPK_B + AVG_B);
    float* hv   = (float*)((char*)d_ws + SPK_B + AVG_B + PAVG_B);

    if (ws_size >= NEED) {
        // split path: conv at ~6 waves/SIMD, LIF memory-bound scan
        k_conv_a<<<dim3(18*256), dim3(256), 0, stream>>>(x, c1w, c1b, b1g, b1b, b1m, b1v,
                                                         c2w, c2b, b2g, b2b, b2m, b2v,
                                                         hv, pavg);
        k_lif_b<<<dim3(NB/256), dim3(256), 0, stream>>>(hv, pavg, spk, avg);
    } else {
        // fallback: round-5 fused kernel (known-pass)
        k_conv_fused<<<dim3(NB/CBLK), dim3(CBLK), 0, stream>>>(x, c1w, c1b, b1g, b1b, b1m, b1v,
                                                               c2w, c2b, b2g, b2b, b2m, b2v,
                                                               spk, avg);
    }
    k_lstm_mfma<<<dim3(NB/64), dim3(256), 0, stream>>>(spk, avg, wih, whh, bih, bhh,
                                                       rw1, rb1, rw2, rb2, fw, fb,
                                                       cw1, cb1, cw2, cb2, out);
}

// Round 7
// 427.154 us; speedup vs baseline: 2.0466x; 2.0466x over previous
//
#include <hip/hip_runtime.h>

#define NB 65536

typedef unsigned long long u64;
typedef __attribute__((ext_vector_type(8))) short short8;   // 8 bf16 (guide-verified typing)
typedef __attribute__((ext_vector_type(4))) float f32x4;

union FragAB { unsigned short us[8]; unsigned w[4]; short8 v; };

__device__ __forceinline__ float fast_rcp(float x){ return __builtin_amdgcn_rcpf(x); }
__device__ __forceinline__ float sigf(float x){ return fast_rcp(1.0f + __expf(-x)); }
__device__ __forceinline__ float tanh_fast(float x){ return 1.0f - 2.0f*fast_rcp(1.0f + __expf(2.0f*x)); }

__device__ __forceinline__ unsigned short f2bf(float f){
    union { float f; unsigned u; } x; x.f = f;
    unsigned r = x.u + 0x7FFFu + ((x.u >> 16) & 1u);   // RNE
    return (unsigned short)(r >> 16);
}
__device__ __forceinline__ float bf2f(unsigned short h){
    union { unsigned u; float f; } x; x.u = ((unsigned)h) << 16; return x.f;
}

// ============ Kernel 1: conv+LIF, chain-parallel (3 threads/sample) ============
// LIF fact: kk = site%33 and site ≡ c2 (mod 3)  =>  chains kk≡R (mod 3) consume only
// channels {R, R+3, R+6, R+9}. Thread (R, sample): full conv1 (redundant, cheap),
// conv2 for its 4 channels (expression trees verbatim from the passing fused kernel
// -> identical FMA contraction -> bit-identical hv), LIF for its 11 chains (identical
// per-chain op order -> bit-identical spikes), 11-bit spike partials per word
// (OR'd exactly in the LSTM kernel), and its 4 channels' complete avg sums.
// R is a template parameter (block-uniform dispatch) so every m1/m2/acc index is
// compile-time -> registers, no scratch. 3x threads -> ~3 waves/SIMD vs 1.
template<int R>
__device__ __forceinline__ void conv_lif_body(
    const float* __restrict__ xr, const int s,
    const float* __restrict__ c1w, const float* __restrict__ c1b,
    const float* __restrict__ b1g, const float* __restrict__ b1b,
    const float* __restrict__ b1m, const float* __restrict__ b1v,
    const float* __restrict__ c2w, const float* __restrict__ c2b,
    const float* __restrict__ b2g, const float* __restrict__ b2b,
    const float* __restrict__ b2m, const float* __restrict__ b2v,
    u64* __restrict__ spkR,            // partial-spike plane for this R
    float* __restrict__ avg)
{
    // conv1 folded weights — verbatim
    float w1f[6][5], c1f[6];
    #pragma unroll
    for (int c = 0; c < 6; ++c) {
        float sc = b1g[c] / sqrtf(b1v[c] + 1e-5f);
        #pragma unroll
        for (int j = 0; j < 5; ++j) w1f[c][j] = c1w[c*5+j] * sc;
        c1f[c] = (c1b[c] - b1m[c]) * sc + b1b[c];
    }
    // bn2 fold for this thread's 4 channels (same formulas/values as fused s2v/t2v)
    float s2c[4], t2c[4];
    #pragma unroll
    for (int j = 0; j < 4; ++j) {
        const int c = R + 3*j;
        float sc = b2g[c] / sqrtf(b2v[c] + 1e-5f);
        s2c[j] = sc;
        t2c[j] = (c2b[c] - b2m[c]) * sc + b2b[c];
    }

    float m1loc[11], m2loc[11];
    #pragma unroll
    for (int k = 0; k < 11; ++k) { m1loc[k] = 0.f; m2loc[k] = 0.f; }

    float sum4[4];
    #pragma unroll
    for (int j = 0; j < 4; ++j) sum4[j] = 0.f;

    float hA[6], hB[6], hC[6];
    #pragma unroll
    for (int c = 0; c < 6; ++c) hA[c] = 0.f;

    #pragma unroll 1
    for (int ss = 0; ss < 8; ++ss) {
        // x window — verbatim from fused kernel
        float xw[52];
        #pragma unroll
        for (int e = 0; e < 13; ++e) {
            int gi = 44*ss - 4 + 4*e;
            float4 v;
            if (gi >= 0) v = *(const float4*)(xr + gi);
            else         v = make_float4(0.f, 0.f, 0.f, 0.f);
            xw[4*e+0] = v.x; xw[4*e+1] = v.y; xw[4*e+2] = v.z; xw[4*e+3] = v.w;
        }

        // 4 spike words per superstep: words 4ss..4ss+3 (sites 132ss..132ss+131)
        u64 accw[4] = {0ull, 0ull, 0ull, 0ull};

        #pragma unroll
        for (int pi = 0; pi < 11; ++pi) {
            const float xv0 = xw[4*pi+2], xv1 = xw[4*pi+3], xv2 = xw[4*pi+4],
                        xv3 = xw[4*pi+5], xv4 = xw[4*pi+6], xv5 = xw[4*pi+7],
                        xv6 = xw[4*pi+8];
            #pragma unroll
            for (int c = 0; c < 6; ++c) {
                float aB = c1f[c] + w1f[c][0]*xv0 + w1f[c][1]*xv1 + w1f[c][2]*xv2
                                  + w1f[c][3]*xv3 + w1f[c][4]*xv4;
                float aC = c1f[c] + w1f[c][0]*xv2 + w1f[c][1]*xv3 + w1f[c][2]*xv4
                                  + w1f[c][3]*xv5 + w1f[c][4]*xv6;
                hB[c] = fmaxf(aB, 0.f);
                hC[c] = fmaxf(aC, 0.f);
            }
            #pragma unroll
            for (int j = 0; j < 4; ++j) {
                const int c2 = R + 3*j;
                float acc = 0.f;
                #pragma unroll
                for (int c1 = 0; c1 < 6; ++c1) {
                    const float* wp = c2w + c2*18 + c1*3;
                    acc += wp[0]*hA[c1] + wp[1]*hB[c1] + wp[2]*hC[c1];
                }
                float hv = fmaxf(acc*s2c[j] + t2c[j], 0.f);
                sum4[j] += hv;

                const int site = 12*pi + c2;     // in-superstep site, compile-time
                const int kk   = site % 33;      // chain id, compile-time
                const int jp   = (kk - R) / 3;   // local chain index 0..10
                const int wr   = site / 33;      // word 0..3 within superstep

                float v1 = 0.95f*m1loc[jp] + hv;
                bool s1 = (v1 > 0.5f);
                m1loc[jp] = s1 ? 0.f : v1;
                float v2 = 0.9f*m2loc[jp] + (s1 ? 1.f : 0.f);
                bool sp2 = (v2 > 0.6f);
                m2loc[jp] = sp2 ? 0.f : v2;
                if (sp2) accw[wr] |= ((u64)1 << kk);
            }
            #pragma unroll
            for (int c = 0; c < 6; ++c) hA[c] = hC[c];
        }

        #pragma unroll
        for (int k = 0; k < 4; ++k)
            spkR[(size_t)(4*ss + k)*NB + s] = accw[k];
    }

    // tail positions 88, 89 (feed avg only) — windows verbatim, 4-channel sums
    {
        float xw2[13];
        float4 q0 = *(const float4*)(xr + 348);
        float4 q1 = *(const float4*)(xr + 352);
        float4 q2 = *(const float4*)(xr + 356);
        xw2[0]=q0.x; xw2[1]=q0.y; xw2[2]=q0.z; xw2[3]=q0.w;
        xw2[4]=q1.x; xw2[5]=q1.y; xw2[6]=q1.z; xw2[7]=q1.w;
        xw2[8]=q2.x; xw2[9]=q2.y; xw2[10]=q2.z; xw2[11]=q2.w;
        xw2[12]=0.f;
        #pragma unroll
        for (int pt = 0; pt < 2; ++pt) {
            const float xv0 = xw2[2+4*pt], xv1 = xw2[3+4*pt], xv2 = xw2[4+4*pt],
                        xv3 = xw2[5+4*pt], xv4 = xw2[6+4*pt], xv5 = xw2[7+4*pt],
                        xv6 = xw2[8+4*pt];
            #pragma unroll
            for (int c = 0; c < 6; ++c) {
                float aB = c1f[c] + w1f[c][0]*xv0 + w1f[c][1]*xv1 + w1f[c][2]*xv2
                                  + w1f[c][3]*xv3 + w1f[c][4]*xv4;
                float aC = c1f[c] + w1f[c][0]*xv2 + w1f[c][1]*xv3 + w1f[c][2]*xv4
                                  + w1f[c][3]*xv5 + w1f[c][4]*xv6;
                hB[c] = fmaxf(aB, 0.f);
                hC[c] = fmaxf(aC, 0.f);
            }
            #pragma unroll
            for (int j = 0; j < 4; ++j) {
                const int c2 = R + 3*j;
                float acc = 0.f;
                #pragma unroll
                for (int c1 = 0; c1 < 6; ++c1) {
                    const float* wp = c2w + c2*18 + c1*3;
                    acc += wp[0]*hA[c1] + wp[1]*hB[c1] + wp[2]*hC[c1];
                }
                sum4[j] += fmaxf(acc*s2c[j] + t2c[j], 0.f);
            }
            #pragma unroll
            for (int c = 0; c < 6; ++c) hA[c] = hC[c];
        }
    }
    #pragma unroll
    for (int j = 0; j < 4; ++j)
        avg[(size_t)(R + 3*j)*NB + s] = sum4[j] / 90.0f;
}

__global__ __launch_bounds__(256)
void k_conv_lif3(const float* __restrict__ x,
                 const float* __restrict__ c1w, const float* __restrict__ c1b,
                 const float* __restrict__ b1g, const float* __restrict__ b1b,
                 const float* __restrict__ b1m, const float* __restrict__ b1v,
                 const float* __restrict__ c2w, const float* __restrict__ c2b,
                 const float* __restrict__ b2g, const float* __restrict__ b2b,
                 const float* __restrict__ b2m, const float* __restrict__ b2v,
                 u64* __restrict__ spkP,
                 float* __restrict__ avg)
{
    const int r = blockIdx.x >> 8;                       // block-uniform
    const int s = ((blockIdx.x & 255) << 8) + threadIdx.x;
    const float* xr = x + (size_t)s * 360;

    if (r == 0)
        conv_lif_body<0>(xr, s, c1w,c1b,b1g,b1b,b1m,b1v,c2w,c2b,b2g,b2b,b2m,b2v,
                         spkP, avg);
    else if (r == 1)
        conv_lif_body<1>(xr, s, c1w,c1b,b1g,b1b,b1m,b1v,c2w,c2b,b2g,b2b,b2m,b2v,
                         spkP + (size_t)32*NB, avg);
    else
        conv_lif_body<2>(xr, s, c1w,c1b,b1g,b1b,b1m,b1v,c2w,c2b,b2g,b2b,b2m,b2v,
                         spkP + (size_t)64*NB, avg);
}

// ============ Kernel 2: MFMA LSTM (split-bf16) + heads — ZERO LDS ============
// Round-5 structure (post-timing-stable). Only delta: spike word = OR of the 3
// chain-partition partials (exact), with the depth-2 prefetch ring widened to 3 streams.
__global__ __launch_bounds__(256, 2)
void k_lstm_mfma(const u64* __restrict__ spk,
                 const float* __restrict__ avg,
                 const float* __restrict__ wih, const float* __restrict__ whh,
                 const float* __restrict__ bih, const float* __restrict__ bhh,
                 const float* __restrict__ rw1, const float* __restrict__ rb1,
                 const float* __restrict__ rw2, const float* __restrict__ rb2,
                 const float* __restrict__ fw,  const float* __restrict__ fb,
                 const float* __restrict__ cw1, const float* __restrict__ cb1,
                 const float* __restrict__ cw2, const float* __restrict__ cb2,
                 float* __restrict__ out)
{
    const int tid  = threadIdx.x;
    const int lane = tid & 63;
    const int wv   = __builtin_amdgcn_readfirstlane(tid >> 6);
    const int q    = lane >> 4;
    const int n16  = lane & 15;
    const int sample = blockIdx.x * 64 + wv * 16 + n16;
    const int q8 = q * 8;

    short8 WihHi[6][2], WihLo[6], WhhHi[6], WhhLo[6];
    #pragma unroll
    for (int m = 0; m < 6; ++m) {
        const int rowA = 16*m + n16;
        const int u    = rowA >> 2;
        const int gt   = rowA & 3;
        const float* wr = wih + (gt*24 + u)*33;
        FragAB fh, fl;
        #pragma unroll
        for (int j = 0; j < 8; ++j) {
            float v = wr[q8 + j];
            unsigned short h = f2bf(v);
            fh.us[j] = h;
            fl.us[j] = f2bf(v - bf2f(h));
        }
        WihHi[m][0] = fh.v; WihLo[m] = fl.v;

        FragAB f1z;
        #pragma unroll
        for (int j = 0; j < 8; ++j) f1z.us[j] = 0;
        if (q == 0) {
            f1z.us[0] = f2bf(wr[32]);
            float bs = bih[gt*24 + u] + bhh[gt*24 + u];
            unsigned short bh = f2bf(bs);
            f1z.us[1] = bh;
            f1z.us[2] = f2bf(bs - bf2f(bh));
        }
        WihHi[m][1] = f1z.v;

        const float* hr = whh + (gt*24 + u)*24;
        FragAB gh, gl;
        #pragma unroll
        for (int j = 0; j < 8; ++j) {
            float v = (j < 6) ? hr[4*j + q] : 0.f;
            unsigned short h = f2bf(v);
            gh.us[j] = (j < 6) ? h : (unsigned short)0;
            gl.us[j] = (j < 6) ? f2bf(v - bf2f(h)) : (unsigned short)0;
        }
        WhhHi[m] = gh.v; WhhLo[m] = gl.v;
    }

    float av3[3];
    #pragma unroll
    for (int i = 0; i < 3; ++i) av3[i] = avg[(size_t)(3*q + i)*NB + sample];

    float cst[6], hreg[6];
    #pragma unroll
    for (int m = 0; m < 6; ++m) { cst[m] = 0.f; hreg[m] = 0.f; }

    // three partial-spike streams, depth-2 prefetch ring
    const u64* sp0 = spk + sample;
    const u64* sp1 = sp0 + (size_t)32*NB;
    const u64* sp2 = sp0 + (size_t)64*NB;
    u64 p0a = sp0[0],            p0b = sp1[0],            p0c = sp2[0];
    u64 p1a = sp0[(size_t)NB],   p1b = sp1[(size_t)NB],   p1c = sp2[(size_t)NB];

    #pragma unroll 1
    for (int t = 0; t < 32; ++t) {
        const u64 wcur = p0a | p0b | p0c;

        u64 p2a = 0, p2b = 0, p2c = 0;
        if (t < 30) {
            const size_t off = (size_t)(t+2)*NB;
            p2a = sp0[off]; p2b = sp1[off]; p2c = sp2[off];
        }

        FragAB BH, BL;
        {
            union { float f; unsigned u; } hu[6];
            #pragma unroll
            for (int m = 0; m < 6; ++m) hu[m].f = hreg[m];
            #pragma unroll
            for (int jp = 0; jp < 3; ++jp) {
                unsigned u0 = hu[2*jp].u, u1 = hu[2*jp+1].u;
                BH.w[jp] = (u0 >> 16) | (u1 & 0xFFFF0000u);
                union { unsigned u; float f; } t0, t1;
                t0.u = u0 & 0xFFFF0000u; t1.u = u1 & 0xFFFF0000u;
                BL.w[jp] = (unsigned)f2bf(hu[2*jp].f - t0.f)
                         | ((unsigned)f2bf(hu[2*jp+1].f - t1.f) << 16);
            }
            BH.w[3] = 0u; BL.w[3] = 0u;
        }

        const unsigned lo32 = (unsigned)wcur;
        const unsigned hi32 = (unsigned)(wcur >> 32);
        FragAB bs0;
        {
            const unsigned byt = (lo32 >> q8) & 0xFFu;
            #pragma unroll
            for (int p = 0; p < 4; ++p) {
                unsigned e0 = (byt >> (2*p)) & 1u;
                unsigned e1 = (byt >> (2*p+1)) & 1u;
                bs0.w[p] = (e0 ? 0x3F80u : 0u) | (e1 ? 0x3F800000u : 0u);
            }
        }
        FragAB bs1;
        bs1.w[0] = 0x3F800000u | ((hi32 & 1u) ? 0x3F80u : 0u);
        bs1.w[1] = 0x00003F80u;
        bs1.w[2] = 0u; bs1.w[3] = 0u;

        f32x4 acc[6];
        #pragma unroll
        for (int m = 0; m < 6; ++m) {
            f32x4 a = {0.f, 0.f, 0.f, 0.f};
            a = __builtin_amdgcn_mfma_f32_16x16x32_bf16(WihHi[m][0], bs0.v, a, 0, 0, 0);
            a = __builtin_amdgcn_mfma_f32_16x16x32_bf16(WihLo[m],    bs0.v, a, 0, 0, 0);
            a = __builtin_amdgcn_mfma_f32_16x16x32_bf16(WihHi[m][1], bs1.v, a, 0, 0, 0);
            a = __builtin_amdgcn_mfma_f32_16x16x32_bf16(WhhHi[m],    BH.v,  a, 0, 0, 0);
            a = __builtin_amdgcn_mfma_f32_16x16x32_bf16(WhhLo[m],    BH.v,  a, 0, 0, 0);
            a = __builtin_amdgcn_mfma_f32_16x16x32_bf16(WhhHi[m],    BL.v,  a, 0, 0, 0);
            acc[m] = a;
        }

        #pragma unroll
        for (int m = 0; m < 6; ++m) {
            float ii = sigf(acc[m][0]);
            float ff = sigf(acc[m][1]);
            float gg = tanh_fast(acc[m][2]);
            float oo = sigf(acc[m][3]);
            float cn = ff*cst[m] + ii*gg;
            cst[m] = cn;
            hreg[m] = oo * tanh_fast(cn);
        }
        p0a = p1a; p0b = p1b; p0c = p1c;
        p1a = p2a; p1b = p2b; p1c = p2c;
    }

    float f1v[12];
    #pragma unroll
    for (int r = 0; r < 12; ++r) {
        float a = 0.f;
        #pragma unroll
        for (int m = 0; m < 6; ++m) a += rw1[r*36 + 4*m + q] * hreg[m];
        #pragma unroll
        for (int i = 0; i < 3; ++i) a += rw1[r*36 + 24 + 3*q + i] * av3[i];
        a += __shfl_xor(a, 16);
        a += __shfl_xor(a, 32);
        f1v[r] = fmaxf(a + rb1[r], 0.f);
    }
    float z0 = rb2[0], z1 = rb2[1];
    #pragma unroll
    for (int r = 0; r < 12; ++r) { z0 += rw2[r]*f1v[r]; z1 += rw2[12+r]*f1v[r]; }
    float mz = fmaxf(z0, z1);
    float e0 = 0.7f*__expf(z0 - mz), e1 = 0.3f*__expf(z1 - mz);
    float alpha = e0 * fast_rcp(e0 + e1);

    float ha[6], sa3[3];
    #pragma unroll
    for (int m = 0; m < 6; ++m) ha[m] = hreg[m]*alpha;
    #pragma unroll
    for (int i = 0; i < 3; ++i) sa3[i] = av3[i]*(1.f - alpha);

    float fuv[24];
    #pragma unroll
    for (int r = 0; r < 24; ++r) {
        float a = 0.f;
        #pragma unroll
        for (int m = 0; m < 6; ++m) a += fw[r*36 + 4*m + q] * ha[m];
        #pragma unroll
        for (int i = 0; i < 3; ++i) a += fw[r*36 + 24 + 3*q + i] * sa3[i];
        a += __shfl_xor(a, 16);
        a += __shfl_xor(a, 32);
        fuv[r] = fmaxf(a + fb[r], 0.f);
    }
    float c1r[3];
    #pragma unroll
    for (int k = 0; k < 3; ++k) {
        const int r = 3*q + k;
        float a = cb1[r];
        #pragma unroll
        for (int u2 = 0; u2 < 24; ++u2) a += cw1[r*24 + u2] * fuv[u2];
        c1r[k] = fmaxf(a, 0.f);
    }
    #pragma unroll
    for (int o = 0; o < 5; ++o) {
        float a = 0.f;
        #pragma unroll
        for (int k = 0; k < 3; ++k) a += cw2[o*12 + 3*q + k] * c1r[k];
        a += __shfl_xor(a, 16);
        a += __shfl_xor(a, 32);
        if (q == 0) out[(size_t)sample*5 + o] = a + cb2[o];
    }
}

extern "C" void kernel_launch(void* const* d_in, const int* in_sizes, int n_in,
                              void* d_out, int out_size, void* d_ws, size_t ws_size,
                              hipStream_t stream) {
    const float* x    = (const float*)d_in[0];
    const float* c1w  = (const float*)d_in[1];
    const float* c1b  = (const float*)d_in[2];
    const float* b1g  = (const float*)d_in[3];
    const float* b1b  = (const float*)d_in[4];
    const float* b1m  = (const float*)d_in[5];
    const float* b1v  = (const float*)d_in[6];
    const float* c2w  = (const float*)d_in[7];
    const float* c2b  = (const float*)d_in[8];
    const float* b2g  = (const float*)d_in[9];
    const float* b2b  = (const float*)d_in[10];
    const float* b2m  = (const float*)d_in[11];
    const float* b2v  = (const float*)d_in[12];
    const float* wih  = (const float*)d_in[13];
    const float* whh  = (const float*)d_in[14];
    const float* bih  = (const float*)d_in[15];
    const float* bhh  = (const float*)d_in[16];
    const float* rw1  = (const float*)d_in[17];
    const float* rb1  = (const float*)d_in[18];
    const float* rw2  = (const float*)d_in[19];
    const float* rb2  = (const float*)d_in[20];
    const float* fw   = (const float*)d_in[21];
    const float* fb   = (const float*)d_in[22];
    const float* cw1  = (const float*)d_in[23];
    const float* cb1  = (const float*)d_in[24];
    const float* cw2  = (const float*)d_in[25];
    const float* cb2  = (const float*)d_in[26];
    float* out = (float*)d_out;

    // workspace: [spkP u64[3][32][NB] = 50.3MB][avg f32[12][NB] = 3.1MB]
    u64*   spkP = (u64*)d_ws;
    float* avg  = (float*)((char*)d_ws + (size_t)3*32*NB*sizeof(u64));

    k_conv_lif3<<<dim3(3*256), dim3(256), 0, stream>>>(x, c1w, c1b, b1g, b1b, b1m, b1v,
                                                       c2w, c2b, b2g, b2b, b2m, b2v,
                                                       spkP, avg);
    k_lstm_mfma<<<dim3(NB/64), dim3(256), 0, stream>>>(spkP, avg, wih, whh, bih, bhh,
                                                       rw1, rb1, rw2, rb2, fw, fb,
                                                       cw1, cb1, cw2, cb2, out);
}